// Round 5
// baseline (144.319 us; speedup 1.0000x reference)
//
#include <hip/hip_runtime.h>
#include <math.h>

#define BSZ    8192
#define DDIM   256
#define SCALE  33.33333333333333f   // 1/0.03
#define C_OFF  34.0f                // fixed LSE offset: |sim*SCALE| <= 33.34
#define SC_L2E 48.08983470f         // SCALE * log2(e)
#define C2     49.05163139f         // C_OFF * log2(e)

typedef float floatx4 __attribute__((ext_vector_type(4)));
typedef long long fp8x8;            // 8 x fp8 e4m3 = one MFMA operand (2 VGPRs)

// pack 8 fp32 -> 8 fp8 e4m3 (HW cvt; format matches the fp8 MFMA operand)
__device__ __forceinline__ fp8x8 cvt8_f8(const float* __restrict__ g)
{
    const float4 lo = *(const float4*)g;
    const float4 hi = *(const float4*)(g + 4);
    int a = __builtin_amdgcn_cvt_pk_fp8_f32(lo.x, lo.y, 0, false);
    a     = __builtin_amdgcn_cvt_pk_fp8_f32(lo.z, lo.w, a, true);
    int b = __builtin_amdgcn_cvt_pk_fp8_f32(hi.x, hi.y, 0, false);
    b     = __builtin_amdgcn_cvt_pk_fp8_f32(hi.z, hi.w, b, true);
    int2 r; r.x = a; r.y = b;
    return *(fp8x8*)&r;
}

// ---------------------------------------------------------------- prep (unchanged)
// zt_perm layout: [cb:64][kc:8][col:128][sl:4] x 8B granules;
// physical slot sp holds k-granule sl = sp ^ ((col>>2)&3).
__global__ __launch_bounds__(256) void prep_kernel(
    const float* __restrict__ za, const float* __restrict__ zt,
    unsigned char* __restrict__ za_f8, unsigned char* __restrict__ zt_perm,
    float* __restrict__ zbase)
{
    const int bid = blockIdx.x, tid = threadIdx.x;
    if (bid < 1024) {
        const int i = (bid * 256 + tid) * 8;
        *(fp8x8*)(za_f8 + i) = cvt8_f8(za + i);
        if (bid < 16) {
            const int z = bid * 1024 + tid * 4;
            *(float4*)&zbase[z] = (float4){0.f, 0.f, 0.f, 0.f};
            if (bid == 0 && tid == 0) {
                zbase[16384] = 0.f;          // total
                ((int*)zbase)[16385] = 0;    // flag
                ((int*)zbase)[16386] = 0;    // cnt
            }
        }
    } else {
        const int S     = (bid - 1024) * 256 + tid;   // global 8-B slot id
        const int chunk = S >> 9, P = S & 511;
        const int col   = P >> 2, sp = P & 3;
        const int sl    = sp ^ ((col >> 2) & 3);
        const int cb    = chunk >> 3, kc = chunk & 7;
        const float* src = zt + (size_t)(cb * 128 + col) * DDIM + kc * 32 + sl * 8;
        *(fp8x8*)(zt_perm + (size_t)S * 8) = cvt8_f8(src);
    }
}

// ---------------------------------------------------------------- sim
// ROUND-5: 128x128 blocks, 2x2 waves of 64x64 tiles, B staged ONCE.
// Evidence so far: R0 (LDS-staged, barriers) 50.9us; R2 (clean 2/CU round,
// half the barriers) 54.3us; R4 (L2-direct, no barriers) 59.4us — all at
// MfmaUtil 22-24%. Residency, barrier count, staging BW, and L2-direct are
// all exonerated. Common defect: 32x128 wave tile -> B-reuse of 2 MFMAs per
// ds_read_b64 (4x the traffic/MFMA of the proven 62%-MfmaUtil structures),
// and phase-alternating K-loops that serialize MFMA vs VALU.
// This version: m-reuse 4 (1 ds_read : 4 MFMA), and the ENTIRE gemm+epilogue
// is one barrier-free region: stage 32KB of B once, __syncthreads once, then
// 32 ds_read + 128 MFMA + epilogue with zero internal syncs -> waves
// free-run and de-phase; compiler schedules ds_reads under MFMAs freely.
// LDS 33KB; grid 4096 = clean multiple of residency. prep layout unchanged.
__global__ __launch_bounds__(256, 2) void sim_fused(
    const unsigned char* __restrict__ za_f8, const unsigned char* __restrict__ zt_perm,
    const int* __restrict__ pid,
    float* __restrict__ s_row, float* __restrict__ s_col,
    float* __restrict__ posv)
{
    __shared__ __align__(16) unsigned char Bs[32768];   // full 128-col x 256-k B block
    __shared__ int   pidc[128];
    __shared__ float colsum[128];

    const int bid  = blockIdx.x;
    const int cb   = bid & 63, band = bid >> 6;         // 64 x 64 block grid
    const int row0 = band * 128, col0 = cb * 128;
    const int tid  = threadIdx.x, lane = tid & 63, wid = tid >> 6;  // wid 0..3
    const int wr   = wid >> 1, wc = wid & 1;            // 2x2 wave grid
    const int q    = lane >> 4, lc = lane & 15;
    const int rbase = row0 + wr * 64;                   // wave's first row
    const int qs8   = (q ^ ((lc >> 2) & 3)) * 8;        // swizzled 8-B k-slot

    if (tid < 128) { pidc[tid] = pid[col0 + tid]; colsum[tid] = 0.f; }

    // stage cb's full 32KB of B: 4 waves x 8KB, width-16 global_load_lds
    {
        const unsigned char* src = zt_perm + (size_t)cb * 32768 + wid * 8192 + lane * 16;
        unsigned char* dst = Bs + wid * 8192 + lane * 16;
        #pragma unroll
        for (int i = 0; i < 8; i++)
            __builtin_amdgcn_global_load_lds(
                (const __attribute__((address_space(1))) void*)(src + i * 1024),
                (__attribute__((address_space(3))) void*)(dst + i * 1024),
                16, 0, 0);
    }

    // A fragments (64 rows x 256 k, fp8) while staging is in flight
    fp8x8 af[4][8];
    #pragma unroll
    for (int m = 0; m < 4; m++) {
        const unsigned char* ga = za_f8 + (size_t)(rbase + m * 16 + lc) * DDIM + q * 8;
        #pragma unroll
        for (int kc = 0; kc < 8; kc++)
            af[m][kc] = *(const fp8x8*)(ga + kc * 32);
    }

    int prw[4][4];
    #pragma unroll
    for (int m = 0; m < 4; m++)
        #pragma unroll
        for (int r = 0; r < 4; r++)
            prw[m][r] = pid[rbase + m * 16 + q * 4 + r];

    __syncthreads();   // drains vmcnt: B, pidc visible. ONLY barrier before flush.

    // ---------------- GEMM: one scheduling region, no syncs
    const unsigned char* bb = Bs + wc * 2048 + lc * 32 + qs8;

    floatx4 acc[4][4];
    #pragma unroll
    for (int m = 0; m < 4; m++)
        #pragma unroll
        for (int n = 0; n < 4; n++)
            acc[m][n] = (floatx4){0.f, 0.f, 0.f, 0.f};

    #pragma unroll
    for (int kc = 0; kc < 8; kc++) {
        fp8x8 bfr[4];
        #pragma unroll
        for (int n = 0; n < 4; n++)
            bfr[n] = *(const fp8x8*)(bb + kc * 4096 + n * 512);
        #pragma unroll
        for (int m = 0; m < 4; m++)
            #pragma unroll
            for (int n = 0; n < 4; n++)
                acc[m][n] = __builtin_amdgcn_mfma_f32_16x16x32_fp8_fp8(
                    af[m][kc], bfr[n], acc[m][n], 0, 0, 0);
    }

    // ---------------- epilogue (once per block)
    int pc[4];
    #pragma unroll
    for (int n = 0; n < 4; n++) pc[n] = pidc[wc * 64 + n * 16 + lc];

    float rowp[16];
    #pragma unroll
    for (int i = 0; i < 16; i++) rowp[i] = 0.f;
    float colp[4] = {0.f, 0.f, 0.f, 0.f};

    #pragma unroll
    for (int m = 0; m < 4; m++) {
        #pragma unroll
        for (int r = 0; r < 4; r++) {
            const int pr = prw[m][r];
            float rsum = 0.f;
            #pragma unroll
            for (int n = 0; n < 4; n++) {
                float e = __builtin_amdgcn_exp2f(fmaf(acc[m][n][r], SC_L2E, -C2));
                e = (pr != pc[n]) ? e : 0.f;
                rsum += e;
                colp[n] += e;
            }
            rowp[m * 4 + r] += rsum;
        }
    }

    // diagonal fixup: block diag iff band==cb; wave diag iff wr==wc;
    // fragment diag iff n==m (compile-time -> direct acc[m][m], no chains)
    if (band == cb && wr == wc) {
        #pragma unroll
        for (int m = 0; m < 4; m++) {
            #pragma unroll
            for (int r = 0; r < 4; r++) {
                const float v = acc[m][m][r];
                float e = __builtin_amdgcn_exp2f(fmaf(v, SC_L2E, -C2));
                const bool own = (lc == q * 4 + r);
                e = own ? e : 0.f;
                rowp[m * 4 + r] += e;
                colp[m] += e;
                if (own) posv[rbase + m * 16 + q * 4 + r] = v * SCALE;
            }
        }
    }

    // col partials: reduce over q (rows within wave), then LDS atomics
    #pragma unroll
    for (int n = 0; n < 4; n++) {
        colp[n] += __shfl_xor(colp[n], 16, 64);
        colp[n] += __shfl_xor(colp[n], 32, 64);
    }
    if (q == 0) {
        #pragma unroll
        for (int n = 0; n < 4; n++)
            atomicAdd(&colsum[wc * 64 + n * 16 + lc], colp[n]);
    }

    // row sums: reduce over lc (cols), every lane owns one distinct row
    #pragma unroll
    for (int i = 0; i < 16; i++) {
        rowp[i] += __shfl_xor(rowp[i], 1, 64);
        rowp[i] += __shfl_xor(rowp[i], 2, 64);
        rowp[i] += __shfl_xor(rowp[i], 4, 64);
        rowp[i] += __shfl_xor(rowp[i], 8, 64);
    }
    float rw = rowp[0];
    #pragma unroll
    for (int idx = 1; idx < 16; idx++)
        rw = (lc == idx) ? rowp[idx] : rw;   // cndmask chain, static indices
    atomicAdd(&s_row[rbase + (lc >> 2) * 16 + q * 4 + (lc & 3)], rw);

    // col flush
    __syncthreads();
    if (tid < 128) atomicAdd(&s_col[col0 + tid], colsum[tid]);
}

// ---------------------------------------------------------------- finalize (+ scalar write)
__global__ __launch_bounds__(256) void finalize_rows(
    const int* __restrict__ pid,
    const float* __restrict__ s_row, const float* __restrict__ s_col,
    const float* __restrict__ posv,
    float* __restrict__ total, int* __restrict__ flag, int* __restrict__ cnt,
    float* __restrict__ out)
{
    const int i = blockIdx.x * 256 + threadIdx.x;
    const float p = posv[i];
    const float c = (logf(s_row[i]) + C_OFF - p)
                  + (logf(s_col[i]) + C_OFF - p);

    float v = c;
    #pragma unroll
    for (int off = 32; off > 0; off >>= 1) v += __shfl_down(v, off, 64);
    if ((threadIdx.x & 63) == 0) atomicAdd(total, v);

    const unsigned long long m = __ballot(pid[i] != pid[0]);
    if (m != 0ull && (threadIdx.x & 63) == 0) atomicOr(flag, 1);

    __syncthreads();
    __threadfence();
    if (threadIdx.x == 0) {
        const int done = atomicAdd(cnt, 1);
        if (done == (int)gridDim.x - 1) {
            const float t = atomicAdd(total, 0.0f);
            const int   f = atomicOr(flag, 0);
            out[0] = f ? t / (2.0f * (float)BSZ) : 0.0f;
        }
    }
}

// ---------------------------------------------------------------- launcher
extern "C" void kernel_launch(void* const* d_in, const int* in_sizes, int n_in,
                              void* d_out, int out_size, void* d_ws, size_t ws_size,
                              hipStream_t stream)
{
    const float* za  = (const float*)d_in[0];
    const float* zt  = (const float*)d_in[1];
    const int*   pid = (const int*)d_in[2];
    float* out = (float*)d_out;

    // ws: za_f8 2MB | zt_perm 2MB | s_row[8192] s_col[8192] total flag cnt posv[8192]
    unsigned char* za_f8   = (unsigned char*)d_ws;
    unsigned char* zt_perm = za_f8 + (size_t)BSZ * DDIM;
    float*  s_row   = (float*)(zt_perm + (size_t)BSZ * DDIM);
    float*  s_col   = s_row + BSZ;
    float*  total   = s_col + BSZ;
    int*    flag    = (int*)(total + 1);
    int*    cnt     = flag + 1;
    float*  posv    = (float*)(cnt + 1);

    prep_kernel<<<dim3(2048), 256, 0, stream>>>(za, zt, za_f8, zt_perm, s_row);

    sim_fused<<<dim3(4096), 256, 0, stream>>>(za_f8, zt_perm, pid,
                                              s_row, s_col, posv);

    finalize_rows<<<dim3(BSZ / 256), 256, 0, stream>>>(
        pid, s_row, s_col, posv, total, flag, cnt, out);
}

// Round 6
// 125.925 us; speedup vs baseline: 1.1461x; 1.1461x over previous
//
#include <hip/hip_runtime.h>
#include <math.h>

#define BSZ    8192
#define DDIM   256
#define SCALE  33.33333333333333f   // 1/0.03
#define C_OFF  34.0f                // fixed LSE offset: |sim*SCALE| <= 33.34
#define SC_L2E 48.08983470f         // SCALE * log2(e)
#define C2     49.05163139f         // C_OFF * log2(e)

typedef float floatx4 __attribute__((ext_vector_type(4)));
typedef long long fp8x8;            // 8 x fp8 e4m3 = one MFMA operand (2 VGPRs)

// pack 8 fp32 -> 8 fp8 e4m3 (HW cvt; format matches the fp8 MFMA operand)
__device__ __forceinline__ fp8x8 cvt8_f8(const float* __restrict__ g)
{
    const float4 lo = *(const float4*)g;
    const float4 hi = *(const float4*)(g + 4);
    int a = __builtin_amdgcn_cvt_pk_fp8_f32(lo.x, lo.y, 0, false);
    a     = __builtin_amdgcn_cvt_pk_fp8_f32(lo.z, lo.w, a, true);
    int b = __builtin_amdgcn_cvt_pk_fp8_f32(hi.x, hi.y, 0, false);
    b     = __builtin_amdgcn_cvt_pk_fp8_f32(hi.z, hi.w, b, true);
    int2 r; r.x = a; r.y = b;
    return *(fp8x8*)&r;
}

// ---------------------------------------------------------------- prep (R0-identical)
// zt_perm layout: strip-major [strip:16][kc:8][col:512][sl:4] x 8B granules;
// physical slot sp holds k-granule sl = sp ^ ((col>>2)&3).
__global__ __launch_bounds__(256) void prep_kernel(
    const float* __restrict__ za, const float* __restrict__ zt,
    unsigned char* __restrict__ za_f8, unsigned char* __restrict__ zt_perm,
    float* __restrict__ zbase)
{
    const int bid = blockIdx.x, tid = threadIdx.x;
    if (bid < 1024) {
        const int i = (bid * 256 + tid) * 8;
        *(fp8x8*)(za_f8 + i) = cvt8_f8(za + i);
        if (bid < 16) {
            const int z = bid * 1024 + tid * 4;
            *(float4*)&zbase[z] = (float4){0.f, 0.f, 0.f, 0.f};
            if (bid == 0 && tid == 0) {
                zbase[16384] = 0.f;          // total
                ((int*)zbase)[16385] = 0;    // flag
                ((int*)zbase)[16386] = 0;    // cnt
            }
        }
    } else {
        const int S     = (bid - 1024) * 256 + tid;   // global 8-B slot id
        const int chunk = S >> 9, P = S & 511;
        const int col   = P >> 2, sp = P & 3;
        const int sl    = sp ^ ((col >> 2) & 3);
        const int cb    = chunk >> 3, kc = chunk & 7;
        const float* src = zt + (size_t)(cb * 128 + col) * DDIM + kc * 32 + sl * 8;
        *(fp8x8*)(zt_perm + (size_t)S * 8) = cvt8_f8(src);
    }
}

// ---------------------------------------------------------------- sim
// ROUND-6: WAVE-PRIVATE double-buffered staging, ZERO K-loop barriers.
// Evidence: R0 (block-shared staging, per-chunk s_barrier) 50.9us @24% Mfma;
// R2 (half the barriers, same lockstep) 54.3; R4 (no barriers, scattered
// L2-direct reads) 59.4; R5 (reuse-4 tile) rematerialized A (VGPR 84) and
// never tested its theory. Diagnosis: block-wide barriers force all waves
// into the same phase -> epilogue VALU and ds-latency never hide under
// MFMAs (24+31=55% busy, 45% dead).
// This version keeps R0's exact per-wave structure (af[2][8], acc[2][8],
// same swizzle, same epilogue; 112 VGPR measured, no spill) but each wave
// stages ITS OWN 4KB chunks (2-deep, vmcnt(4) counted, lgkmcnt(0) before
// reusing the buffer) -> fully self-contained per-wave pipeline, no
// s_barrier anywhere in the K loop. LDS 37KB -> 4 blocks/CU = 16 waves/CU,
// all free-running: one wave's ds-latency/epilogue hides under others'
// MFMAs. Cost: 4x L2 traffic on zt_perm (2MB, L2-resident; ~1.6TB/s per
// XCD vs 4.3 available). Spill tripwire: FETCH must stay ~9.4MB.
__global__ __launch_bounds__(256, 2) void sim_fused(
    const unsigned char* __restrict__ za_f8, const unsigned char* __restrict__ zt_perm,
    const int* __restrict__ pid,
    float* __restrict__ s_row, float* __restrict__ s_col,
    float* __restrict__ posv)
{
    __shared__ __align__(16) unsigned char Bs[4][8192];   // per-wave 2 x 4KB dbuf
    __shared__ int   pidc[512];
    __shared__ float colsum[512];

    const int bid   = blockIdx.x;
    const int strip = bid & 15, band = bid >> 4;          // band 0..63
    const int row0  = band * 128, scol0 = strip * 512;
    const int tid   = threadIdx.x, lane = tid & 63, wid = tid >> 6;  // wid 0..3
    const int q     = lane >> 4, lc = lane & 15;
    const int rbase = row0 + wid * 32;
    const int qs8   = (q ^ ((lc >> 2) & 3)) * 8;   // swizzled 8-B k-slot offset

    pidc[tid]         = pid[scol0 + tid];
    pidc[tid + 256]   = pid[scol0 + tid + 256];
    colsum[tid]       = 0.f;
    colsum[tid + 256] = 0.f;

    // per-lane source base (lane*16 per global_load_lds semantics: per-lane
    // global src, wave-uniform LDS dst) and this wave's private LDS buffer
    const unsigned char* zp = zt_perm + (size_t)strip * 131072 + lane * 16;
    unsigned char* wbuf = &Bs[wid][0];

    // chunk c (c=t*8+kc, 4KB = 128 cols x 32 k) src offset: (c&7)*16384 + (c>>3)*4096
#define WSTAGE(so, doff)                                                         \
    do {                                                                         \
        const unsigned char* _s = zp + (so);                                     \
        unsigned char* _d = wbuf + (doff);                                       \
        _Pragma("unroll")                                                        \
        for (int _i = 0; _i < 4; _i++)                                           \
            __builtin_amdgcn_global_load_lds(                                    \
                (const __attribute__((address_space(1))) void*)(_s + _i * 1024), \
                (__attribute__((address_space(3))) void*)(_d + _i * 1024),       \
                16, 0, 0);                                                       \
    } while (0)

    // prologue: stage chunks 0 (kc=0) and 1 (kc=1)
    WSTAGE(0, 0);
    WSTAGE(16384, 4096);

    // A fragments resident: af[m][kc] = A[rbase+m*16+lc][kc*32 + q*8 ..+8] (fp8)
    fp8x8 af[2][8];
    #pragma unroll
    for (int m = 0; m < 2; m++) {
        const unsigned char* ga = za_f8 + (size_t)(rbase + m * 16 + lc) * DDIM + q * 8;
        #pragma unroll
        for (int kc = 0; kc < 8; kc++)
            af[m][kc] = *(const fp8x8*)(ga + kc * 32);
    }

    int prw[2][4];
    #pragma unroll
    for (int m = 0; m < 2; m++)
        #pragma unroll
        for (int r = 0; r < 4; r++)
            prw[m][r] = pid[rbase + m * 16 + q * 4 + r];

    __syncthreads();   // one-time: pidc/colsum visible (also drains prologue vmem)

    float rowp[8] = {0.f, 0.f, 0.f, 0.f, 0.f, 0.f, 0.f, 0.f};
    const int diag_t = (row0 - scol0) >> 7;   // tile holding the diagonal (if in [0,4))

    for (int t = 0; t < 4; t++) {
        floatx4 acc[2][8];
        #pragma unroll
        for (int m = 0; m < 2; m++)
            #pragma unroll
            for (int n = 0; n < 8; n++)
                acc[m][n] = (floatx4){0.f, 0.f, 0.f, 0.f};

        #pragma unroll
        for (int kc = 0; kc < 8; kc++) {
            // wait: all but the newest staged chunk complete -> chunk (t,kc) ready
            if (kc == 7 && t == 3)
                __asm__ volatile("s_waitcnt vmcnt(0)" ::: "memory");
            else
                __asm__ volatile("s_waitcnt vmcnt(4)" ::: "memory");

            const unsigned char* B = wbuf + (kc & 1) * 4096;
            fp8x8 bfr[8];
            #pragma unroll
            for (int n = 0; n < 8; n++)
                bfr[n] = *(const fp8x8*)(B + (n * 16 + lc) * 32 + qs8);

            // own ds_reads retired -> safe to overwrite this half-buffer
            __asm__ volatile("s_waitcnt lgkmcnt(0)" ::: "memory");
            {
                const int c2 = t * 8 + kc + 2;
                if (c2 < 32)
                    WSTAGE(((size_t)(c2 & 7)) * 16384 + ((size_t)(c2 >> 3)) * 4096,
                           (kc & 1) * 4096);
            }

            #pragma unroll
            for (int m = 0; m < 2; m++)
                #pragma unroll
                for (int n = 0; n < 8; n++)
                    acc[m][n] = __builtin_amdgcn_mfma_f32_16x16x32_fp8_fp8(
                        af[m][kc], bfr[n], acc[m][n], 0, 0, 0);
        }

        // ---------- epilogue for tile t (wave-local; no sync with other waves)
        int pc[8];
        #pragma unroll
        for (int n = 0; n < 8; n++) pc[n] = pidc[t * 128 + n * 16 + lc];

        float colp[8] = {0.f, 0.f, 0.f, 0.f, 0.f, 0.f, 0.f, 0.f};
        #pragma unroll
        for (int m = 0; m < 2; m++) {
            #pragma unroll
            for (int r = 0; r < 4; r++) {
                const int pr = prw[m][r];
                float rsum = 0.f;
                #pragma unroll
                for (int n = 0; n < 8; n++) {
                    float e = __builtin_amdgcn_exp2f(fmaf(acc[m][n][r], SC_L2E, -C2));
                    e = (pr != pc[n]) ? e : 0.f;
                    rsum += e;
                    colp[n] += e;
                }
                rowp[m * 4 + r] += rsum;
            }
        }

        if (t == diag_t) {   // diagonal fixup — constant-index select chains only
            #pragma unroll
            for (int m = 0; m < 2; m++) {
                const int nstar = wid * 2 + m;
                #pragma unroll
                for (int r = 0; r < 4; r++) {
                    float v = 0.f;
                    #pragma unroll
                    for (int n = 0; n < 8; n++)
                        v = (n == nstar) ? acc[m][n][r] : v;   // cndmask chain
                    float e = __builtin_amdgcn_exp2f(fmaf(v, SC_L2E, -C2));
                    const bool own = (lc == q * 4 + r);
                    e = own ? e : 0.f;
                    rowp[m * 4 + r] += e;
                    #pragma unroll
                    for (int n = 0; n < 8; n++)
                        colp[n] += (n == nstar) ? e : 0.f;     // cndmask chain
                    if (own) posv[rbase + m * 16 + q * 4 + r] = v * SCALE;
                }
            }
        }

        #pragma unroll
        for (int n = 0; n < 8; n++) {
            colp[n] += __shfl_xor(colp[n], 16, 64);
            colp[n] += __shfl_xor(colp[n], 32, 64);
        }
        if (q == 0) {
            #pragma unroll
            for (int n = 0; n < 8; n++)
                atomicAdd(&colsum[t * 128 + n * 16 + lc], colp[n]);
        }
    }

    // ---------- row sums: reduce over lc (cols), one atomic per row
    #pragma unroll
    for (int i = 0; i < 8; i++) {
        rowp[i] += __shfl_xor(rowp[i], 1, 64);
        rowp[i] += __shfl_xor(rowp[i], 2, 64);
        rowp[i] += __shfl_xor(rowp[i], 4, 64);
        rowp[i] += __shfl_xor(rowp[i], 8, 64);
    }
    float rw = rowp[0];
    #pragma unroll
    for (int idx = 1; idx < 8; idx++)
        rw = (lc == idx) ? rowp[idx] : rw;
    if (lc < 8)
        atomicAdd(&s_row[rbase + (lc >> 2) * 16 + q * 4 + (lc & 3)], rw);

    // ---------- col sums
    __syncthreads();
    atomicAdd(&s_col[scol0 + tid], colsum[tid]);
    atomicAdd(&s_col[scol0 + tid + 256], colsum[tid + 256]);
#undef WSTAGE
}

// ---------------------------------------------------------------- finalize (+ scalar write)
__global__ __launch_bounds__(256) void finalize_rows(
    const int* __restrict__ pid,
    const float* __restrict__ s_row, const float* __restrict__ s_col,
    const float* __restrict__ posv,
    float* __restrict__ total, int* __restrict__ flag, int* __restrict__ cnt,
    float* __restrict__ out)
{
    const int i = blockIdx.x * 256 + threadIdx.x;
    const float p = posv[i];
    const float c = (logf(s_row[i]) + C_OFF - p)
                  + (logf(s_col[i]) + C_OFF - p);

    float v = c;
    #pragma unroll
    for (int off = 32; off > 0; off >>= 1) v += __shfl_down(v, off, 64);
    if ((threadIdx.x & 63) == 0) atomicAdd(total, v);

    const unsigned long long m = __ballot(pid[i] != pid[0]);
    if (m != 0ull && (threadIdx.x & 63) == 0) atomicOr(flag, 1);

    __syncthreads();
    __threadfence();
    if (threadIdx.x == 0) {
        const int done = atomicAdd(cnt, 1);
        if (done == (int)gridDim.x - 1) {
            const float t = atomicAdd(total, 0.0f);
            const int   f = atomicOr(flag, 0);
            out[0] = f ? t / (2.0f * (float)BSZ) : 0.0f;
        }
    }
}

// ---------------------------------------------------------------- launcher
extern "C" void kernel_launch(void* const* d_in, const int* in_sizes, int n_in,
                              void* d_out, int out_size, void* d_ws, size_t ws_size,
                              hipStream_t stream)
{
    const float* za  = (const float*)d_in[0];
    const float* zt  = (const float*)d_in[1];
    const int*   pid = (const int*)d_in[2];
    float* out = (float*)d_out;

    // ws: za_f8 2MB | zt_perm 2MB | s_row[8192] s_col[8192] total flag cnt posv[8192]
    unsigned char* za_f8   = (unsigned char*)d_ws;
    unsigned char* zt_perm = za_f8 + (size_t)BSZ * DDIM;
    float*  s_row   = (float*)(zt_perm + (size_t)BSZ * DDIM);
    float*  s_col   = s_row + BSZ;
    float*  total   = s_col + BSZ;
    int*    flag    = (int*)(total + 1);
    int*    cnt     = flag + 1;
    float*  posv    = (float*)(cnt + 1);

    prep_kernel<<<dim3(2048), 256, 0, stream>>>(za, zt, za_f8, zt_perm, s_row);

    sim_fused<<<dim3(1024), 256, 0, stream>>>(za_f8, zt_perm, pid,
                                              s_row, s_col, posv);

    finalize_rows<<<dim3(BSZ / 256), 256, 0, stream>>>(
        pid, s_row, s_col, posv, total, flag, cnt, out);
}

// Round 7
// 120.340 us; speedup vs baseline: 1.1993x; 1.0464x over previous
//
#include <hip/hip_runtime.h>
#include <math.h>

#define BSZ    8192
#define DDIM   256
#define SCALE  33.33333333333333f   // 1/0.03
#define C_OFF  34.0f                // fixed LSE offset: |sim*SCALE| <= 33.34
#define SC_L2E 48.08983470f         // SCALE * log2(e)
#define C2     49.05163139f         // C_OFF * log2(e)

typedef float floatx4  __attribute__((ext_vector_type(4)));
typedef float floatx16 __attribute__((ext_vector_type(16)));
typedef int   intx4    __attribute__((ext_vector_type(4)));
typedef int   intx8    __attribute__((ext_vector_type(8)));
typedef long long fp8x8;            // 8 x fp8 e4m3

// pack 8 fp32 -> 8 fp8 e4m3 (HW cvt; format matches the fp8 MFMA operand)
__device__ __forceinline__ fp8x8 cvt8_f8(const float* __restrict__ g)
{
    const float4 lo = *(const float4*)g;
    const float4 hi = *(const float4*)(g + 4);
    int a = __builtin_amdgcn_cvt_pk_fp8_f32(lo.x, lo.y, 0, false);
    a     = __builtin_amdgcn_cvt_pk_fp8_f32(lo.z, lo.w, a, true);
    int b = __builtin_amdgcn_cvt_pk_fp8_f32(hi.x, hi.y, 0, false);
    b     = __builtin_amdgcn_cvt_pk_fp8_f32(hi.z, hi.w, b, true);
    int2 r; r.x = a; r.y = b;
    return *(fp8x8*)&r;
}

// ---------------------------------------------------------------- prep
// za_f8: row-major [8192][256] fp8.
// zt_perm NEW layout (derived both directions, R6 lesson):
//   byte(cb,col,gph,off) = cb*32768 + col*256 + gph*16 + off
//   physical granule gph holds LOGICAL k-granule kg = gph ^ (col&15)
//   (XOR swizzle so sim's stride-256 ds_read_b128 is bank-conflict-free).
__global__ __launch_bounds__(256) void prep_kernel(
    const float* __restrict__ za, const float* __restrict__ zt,
    unsigned char* __restrict__ za_f8, unsigned char* __restrict__ zt_perm,
    float* __restrict__ zbase)
{
    const int bid = blockIdx.x, tid = threadIdx.x;
    if (bid < 1024) {
        const int i = (bid * 256 + tid) * 8;
        *(fp8x8*)(za_f8 + i) = cvt8_f8(za + i);
        if (bid < 16) {
            const int z = bid * 1024 + tid * 4;
            *(float4*)&zbase[z] = (float4){0.f, 0.f, 0.f, 0.f};
            if (bid == 0 && tid == 0) {
                zbase[16384] = 0.f;          // total
                ((int*)zbase)[16385] = 0;    // flag
                ((int*)zbase)[16386] = 0;    // cnt
            }
        }
    } else {
        const int S    = (bid - 1024) * 256 + tid;   // global 8-B slot id
        const int cbb  = S >> 12;                    // col-block 0..63
        const int col  = (S >> 5) & 127;             // col within block
        const int gph  = (S >> 1) & 15;              // physical 16B granule
        const int off8 = (S & 1) * 8;
        const int k    = ((gph ^ (col & 15)) << 4) + off8;  // logical k byte
        const float* src = zt + (size_t)(cbb * 128 + col) * DDIM + k;
        *(fp8x8*)(zt_perm + (size_t)S * 8) = cvt8_f8(src);
    }
}

// ---------------------------------------------------------------- sim
// ROUND-7: MX-scaled v_mfma_f32_32x32x64_f8f6f4 (unit scales) core.
// Evidence R0-R6: every schedule variant = 51-60us @ MfmaUtil 22-25%;
// per-SIMD arithmetic: MFMA pipe 16.8us + VALU ~15us, unoverlappable at
// source level. So shrink the terms: scaled-MFMA fp8 = 4686 TF (2.3x) ->
// floor 7.3us; MFMA instrs/wave 512->16, ds_reads 256->32, K-loop VALU ~8x
// less. Block 128x128, 4 waves x (32 rows x 128 cols); B (32KB) staged once,
// ONE syncthreads, then barrier-free compute+epilogue (waves de-phase).
// Correctness-by-construction notes:
//  - A and B loaded with the SAME lane->k convention; MFMA k-sum is
//    invariant under consistent operand k-permutation -> exact result even
//    if the HW lane->k map differs from assumption.
//  - C/D layout 32x32: col=lane&31, row=(reg&3)+8*(reg>>2)+4*(lane>>5)
//    (HW-verified m74/m101, dtype-independent).
//  - scale word 0x7F7F7F7F: every e8m0 byte = 2^0 -> any opsel reads 1.0.
//  - LDS swizzle: ds addr granule = kg ^ (col&15); with per-lane base
//    t16=((2h)^s)<<4 and static c<<4, addr = dsb ^ (c<<4) (low-byte XOR).
//    Bank quads = (c ^ lane&7) -> 8 lanes/quad uniform = stride-1-equiv.
__global__ __launch_bounds__(256, 2) void sim_fused(
    const unsigned char* __restrict__ za_f8, const unsigned char* __restrict__ zt_perm,
    const int* __restrict__ pid,
    float* __restrict__ s_row, float* __restrict__ s_col,
    float* __restrict__ posv)
{
    __shared__ __align__(16) unsigned char Bs[32768];   // 128 cols x 256 k fp8
    __shared__ int   pidc[128];
    __shared__ float colsum[128];

    const int bid   = blockIdx.x;
    const int cbb   = bid & 63, band = bid >> 6;        // 64x64 block grid
    const int row0  = band * 128, col0g = cbb * 128;
    const int tid   = threadIdx.x, lane = tid & 63, wid = tid >> 6;
    const int l31   = lane & 31, h = lane >> 5;
    const int rbase = row0 + wid * 32;                  // wave's 32 rows

    if (tid < 128) { pidc[tid] = pid[col0g + tid]; colsum[tid] = 0.f; }

    // ---- stage B: 32KB, 4 waves x 8KB, width-16 global_load_lds (linear)
    {
        const unsigned char* src = zt_perm + (size_t)cbb * 32768 + wid * 8192 + lane * 16;
        unsigned char* dst = Bs + wid * 8192 + lane * 16;
        #pragma unroll
        for (int i = 0; i < 8; i++)
            __builtin_amdgcn_global_load_lds(
                (const __attribute__((address_space(1))) void*)(src + i * 1024),
                (__attribute__((address_space(3))) void*)(dst + i * 1024),
                16, 0, 0);
    }

    // ---- A fragments: lane holds row l31, k = h*32 + ks*64 .. +32 (32B each)
    intx8 af[4];
    {
        const unsigned char* ga = za_f8 + (size_t)(rbase + l31) * DDIM + h * 32;
        #pragma unroll
        for (int ks = 0; ks < 4; ks++)
            af[ks] = *(const intx8*)(ga + ks * 64);
    }

    // row pids: row(reg) = rbase + (reg&3) + 8*(reg>>2) + 4*h
    int prw[16];
    #pragma unroll
    for (int reg = 0; reg < 16; reg++)
        prw[reg] = pid[rbase + (reg & 3) + 8 * (reg >> 2) + 4 * h];

    __syncthreads();   // drains staging vmcnt; pidc/colsum visible. ONLY barrier.

    // ---- GEMM: 32 ds_read_b128 + 16 mfma_scale, one scheduling region
    const int t16 = ((((lane >> 4) & 2) ^ (lane & 15)) << 4);  // ((2h)^s)<<4
    int dsb[4];
    #pragma unroll
    for (int n = 0; n < 4; n++)
        dsb[n] = n * 8192 + l31 * 256 + t16;

    floatx16 acc[4];
    #pragma unroll
    for (int n = 0; n < 4; n++) acc[n] = (floatx16)0.0f;

    #pragma unroll
    for (int ks = 0; ks < 4; ks++) {
        #pragma unroll
        for (int n = 0; n < 4; n++) {
            intx4 lo = *(const intx4*)(Bs + (dsb[n] ^ (((ks * 4 + 0)) << 4)));
            intx4 hi = *(const intx4*)(Bs + (dsb[n] ^ (((ks * 4 + 1)) << 4)));
            intx8 b;
            b[0] = lo[0]; b[1] = lo[1]; b[2] = lo[2]; b[3] = lo[3];
            b[4] = hi[0]; b[5] = hi[1]; b[6] = hi[2]; b[7] = hi[3];
            acc[n] = __builtin_amdgcn_mfma_scale_f32_32x32x64_f8f6f4(
                af[ks], b, acc[n], 0, 0, 0, 0x7F7F7F7F, 0, 0x7F7F7F7F);
        }
    }

    // ---- epilogue (wave-local, no syncs)
    int pc[4];
    #pragma unroll
    for (int n = 0; n < 4; n++) pc[n] = pidc[n * 32 + l31];

    float rowp[16];
    #pragma unroll
    for (int i = 0; i < 16; i++) rowp[i] = 0.f;
    float colp4[4] = {0.f, 0.f, 0.f, 0.f};

    const bool diagblk = (band == cbb);
    const int  target  = (lane & 3) + 4 * ((lane >> 3) & 3);  // reg holding diag
    const bool ownl    = (h == ((lane >> 2) & 1));            // h matches row bit2

    #pragma unroll
    for (int n = 0; n < 4; n++) {
        const int pcn = pc[n];
        #pragma unroll
        for (int reg = 0; reg < 16; reg++) {
            float e = __builtin_amdgcn_exp2f(fmaf(acc[n][reg], SC_L2E, -C2));
            e = (prw[reg] != pcn) ? e : 0.f;
            colp4[n] += e;
            rowp[reg] += e;
        }
        if (diagblk && n == wid) {   // wave-uniform branch
            float vd = 0.f;
            #pragma unroll
            for (int reg = 0; reg < 16; reg++)
                vd = (reg == target) ? acc[n][reg] : vd;       // cndmask chain
            float ed = __builtin_amdgcn_exp2f(fmaf(vd, SC_L2E, -C2));
            ed = ownl ? ed : 0.f;
            colp4[n] += ed;
            #pragma unroll
            for (int reg = 0; reg < 16; reg++)
                rowp[reg] += (reg == target) ? ed : 0.f;       // ed=0 if !ownl
            if (ownl) posv[row0 + wid * 32 + l31] = vd * SCALE;
        }
    }

    // col sums: halves hold disjoint row sets -> one xor32 completes the col
    #pragma unroll
    for (int n = 0; n < 4; n++)
        colp4[n] += __shfl_xor(colp4[n], 32, 64);
    if (lane < 32) {
        #pragma unroll
        for (int n = 0; n < 4; n++)
            atomicAdd(&colsum[n * 32 + lane], colp4[n]);
    }

    // row sums: split-tree reduce of rowp[16] over the 32-lane half
    // (16 shfl total vs 80 for naive butterfly). reg bit assignment:
    // bit3<-lane0, bit2<-lane1, bit1<-lane2, bit0<-lane3.
#define RED(bit, c)                                                        \
    _Pragma("unroll")                                                      \
    for (int _i = 0; _i < (c); _i++) {                                     \
        float _s = (lane & (bit)) ? rowp[_i] : rowp[_i + (c)];             \
        float _o = __shfl_xor(_s, (bit), 64);                              \
        rowp[_i] = ((lane & (bit)) ? rowp[_i + (c)] : rowp[_i]) + _o;      \
    }
    RED(1, 8) RED(2, 4) RED(4, 2) RED(8, 1)
#undef RED
    rowp[0] += __shfl_xor(rowp[0], 16, 64);
    if ((lane & 16) == 0) {
        const int reg = ((lane & 1) << 3) | ((lane & 2) << 1)
                      | ((lane & 4) >> 1) | ((lane & 8) >> 3);
        const int rl  = (reg & 3) + 8 * (reg >> 2) + 4 * h;
        atomicAdd(&s_row[rbase + rl], rowp[0]);
    }

    // col flush
    __syncthreads();
    if (tid < 128) atomicAdd(&s_col[col0g + tid], colsum[tid]);
}

// ---------------------------------------------------------------- finalize (+ scalar write)
__global__ __launch_bounds__(256) void finalize_rows(
    const int* __restrict__ pid,
    const float* __restrict__ s_row, const float* __restrict__ s_col,
    const float* __restrict__ posv,
    float* __restrict__ total, int* __restrict__ flag, int* __restrict__ cnt,
    float* __restrict__ out)
{
    const int i = blockIdx.x * 256 + threadIdx.x;
    const float p = posv[i];
    const float c = (logf(s_row[i]) + C_OFF - p)
                  + (logf(s_col[i]) + C_OFF - p);

    float v = c;
    #pragma unroll
    for (int off = 32; off > 0; off >>= 1) v += __shfl_down(v, off, 64);
    if ((threadIdx.x & 63) == 0) atomicAdd(total, v);

    const unsigned long long m = __ballot(pid[i] != pid[0]);
    if (m != 0ull && (threadIdx.x & 63) == 0) atomicOr(flag, 1);

    __syncthreads();
    __threadfence();
    if (threadIdx.x == 0) {
        const int done = atomicAdd(cnt, 1);
        if (done == (int)gridDim.x - 1) {
            const float t = atomicAdd(total, 0.0f);
            const int   f = atomicOr(flag, 0);
            out[0] = f ? t / (2.0f * (float)BSZ) : 0.0f;
        }
    }
}

// ---------------------------------------------------------------- launcher
extern "C" void kernel_launch(void* const* d_in, const int* in_sizes, int n_in,
                              void* d_out, int out_size, void* d_ws, size_t ws_size,
                              hipStream_t stream)
{
    const float* za  = (const float*)d_in[0];
    const float* zt  = (const float*)d_in[1];
    const int*   pid = (const int*)d_in[2];
    float* out = (float*)d_out;

    // ws: za_f8 2MB | zt_perm 2MB | s_row[8192] s_col[8192] total flag cnt posv[8192]
    unsigned char* za_f8   = (unsigned char*)d_ws;
    unsigned char* zt_perm = za_f8 + (size_t)BSZ * DDIM;
    float*  s_row   = (float*)(zt_perm + (size_t)BSZ * DDIM);
    float*  s_col   = s_row + BSZ;
    float*  total   = s_col + BSZ;
    int*    flag    = (int*)(total + 1);
    int*    cnt     = flag + 1;
    float*  posv    = (float*)(cnt + 1);

    prep_kernel<<<dim3(2048), 256, 0, stream>>>(za, zt, za_f8, zt_perm, s_row);

    sim_fused<<<dim3(4096), 256, 0, stream>>>(za_f8, zt_perm, pid,
                                              s_row, s_col, posv);

    finalize_rows<<<dim3(BSZ / 256), 256, 0, stream>>>(
        pid, s_row, s_col, posv, total, flag, cnt, out);
}

// Round 8
// 101.974 us; speedup vs baseline: 1.4153x; 1.1801x over previous
//
#include <hip/hip_runtime.h>
#include <math.h>

#define BSZ    8192
#define DDIM   256
#define SCALE  33.33333333333333f   // 1/0.03
#define C_OFF  34.0f                // fixed LSE offset: |sim*SCALE| <= 33.34
#define SC_L2E 48.08983470f         // SCALE * log2(e)
#define C2     49.05163139f         // C_OFF * log2(e)

typedef float floatx4  __attribute__((ext_vector_type(4)));
typedef float floatx16 __attribute__((ext_vector_type(16)));
typedef int   intx4    __attribute__((ext_vector_type(4)));
typedef int   intx8    __attribute__((ext_vector_type(8)));
typedef long long fp8x8;            // 8 x fp8 e4m3

// pack 8 fp32 -> 8 fp8 e4m3 (HW cvt; format matches the fp8 MFMA operand)
__device__ __forceinline__ fp8x8 cvt8_f8(const float* __restrict__ g)
{
    const float4 lo = *(const float4*)g;
    const float4 hi = *(const float4*)(g + 4);
    int a = __builtin_amdgcn_cvt_pk_fp8_f32(lo.x, lo.y, 0, false);
    a     = __builtin_amdgcn_cvt_pk_fp8_f32(lo.z, lo.w, a, true);
    int b = __builtin_amdgcn_cvt_pk_fp8_f32(hi.x, hi.y, 0, false);
    b     = __builtin_amdgcn_cvt_pk_fp8_f32(hi.z, hi.w, b, true);
    int2 r; r.x = a; r.y = b;
    return *(fp8x8*)&r;
}

// ---------------------------------------------------------------- prep (R7-identical)
// za_f8: row-major [8192][256] fp8.
// zt_perm layout: byte(cb,col,gph,off) = cb*32768 + col*256 + gph*16 + off;
// physical granule gph holds LOGICAL k-granule kg = gph ^ (col&15).
__global__ __launch_bounds__(256) void prep_kernel(
    const float* __restrict__ za, const float* __restrict__ zt,
    unsigned char* __restrict__ za_f8, unsigned char* __restrict__ zt_perm,
    float* __restrict__ zbase)
{
    const int bid = blockIdx.x, tid = threadIdx.x;
    if (bid < 1024) {
        const int i = (bid * 256 + tid) * 8;
        *(fp8x8*)(za_f8 + i) = cvt8_f8(za + i);
        if (bid < 16) {
            const int z = bid * 1024 + tid * 4;
            *(float4*)&zbase[z] = (float4){0.f, 0.f, 0.f, 0.f};
            if (bid == 0 && tid == 0) {
                zbase[16384] = 0.f;          // total
                ((int*)zbase)[16385] = 0;    // flag
                ((int*)zbase)[16386] = 0;    // cnt
            }
        }
    } else {
        const int S    = (bid - 1024) * 256 + tid;   // global 8-B slot id
        const int cbb  = S >> 12;                    // col-block 0..63
        const int col  = (S >> 5) & 127;             // col within block
        const int gph  = (S >> 1) & 15;              // physical 16B granule
        const int off8 = (S & 1) * 8;
        const int k    = ((gph ^ (col & 15)) << 4) + off8;  // logical k byte
        const float* src = zt + (size_t)(cbb * 128 + col) * DDIM + k;
        *(fp8x8*)(zt_perm + (size_t)S * 8) = cvt8_f8(src);
    }
}

// ---------------------------------------------------------------- sim
// ROUND-8: PERSISTENT blocks. 512 blocks (= exactly 2/CU, resident for the
// whole kernel), each owns col-block cbb and runs 8 band-tiles in sequence.
// Evidence: R0-R7 all land 51-58us regardless of MFMA work (R7 cut MFMA to
// ~6.5us, MfmaUtil 12%), VALU work, barriers, or reuse -> the invariant is
// thousands of SHORT blocks each paying a serial stage->drain->compute->
// flush chain with ~1.4 resident blocks/CU average (measured Occupancy
// ~18% in every round). This version: B (32KB) staged ONCE and PINNED in
// LDS (immutable -> the 8-tile loop has ZERO syncthreads); per tile only A
// changes (128B/lane, software-pipelined one tile ahead, hides under ~2200cy
// of MFMA); col partials accumulate in regs across tiles (8x fewer atomics);
// same-cbb blocks (bid = cbb + 64g, bid%8 = cbb%8) share one XCD's L2 -> B
// fetched from HBM once. Per-tile math byte-identical to R7 (absmax 0.0).
// Spill tripwire: peak regs ~127; FETCH must stay ~9.4MB.
__global__ __launch_bounds__(256, 2) void sim_fused(
    const unsigned char* __restrict__ za_f8, const unsigned char* __restrict__ zt_perm,
    const int* __restrict__ pid,
    float* __restrict__ s_row, float* __restrict__ s_col,
    float* __restrict__ posv)
{
    __shared__ __align__(16) unsigned char Bs[32768];   // 128 cols x 256 k fp8
    __shared__ int   pidc[128];
    __shared__ float colsum[128];

    const int bid   = blockIdx.x;
    const int cbb   = bid & 63;          // column block (fixed for this block)
    const int bgrp  = bid >> 6;          // 0..7 -> bands bgrp*8 .. bgrp*8+7
    const int col0g = cbb * 128;
    const int tid   = threadIdx.x, lane = tid & 63, wid = tid >> 6;
    const int l31   = lane & 31, h = lane >> 5;

    if (tid < 128) { pidc[tid] = pid[col0g + tid]; colsum[tid] = 0.f; }

    // ---- stage B once: 32KB, 4 waves x 8KB, width-16 global_load_lds
    {
        const unsigned char* src = zt_perm + (size_t)cbb * 32768 + wid * 8192 + lane * 16;
        unsigned char* dst = Bs + wid * 8192 + lane * 16;
        #pragma unroll
        for (int i = 0; i < 8; i++)
            __builtin_amdgcn_global_load_lds(
                (const __attribute__((address_space(1))) void*)(src + i * 1024),
                (__attribute__((address_space(3))) void*)(dst + i * 1024),
                16, 0, 0);
    }

    // ---- tile-0 A fragments (prefetch while staging is in flight)
    const int band0 = bgrp * 8;
    intx8 afc[4];
    {
        const unsigned char* ga =
            za_f8 + (size_t)(band0 * 128 + wid * 32 + l31) * DDIM + h * 32;
        #pragma unroll
        for (int ks = 0; ks < 4; ks++)
            afc[ks] = *(const intx8*)(ga + ks * 64);
    }

    __syncthreads();   // B + pidc visible. ONLY barrier until the final flush.

    // ds_read bases for B (fixed across all 8 tiles)
    const int t16 = ((((lane >> 4) & 2) ^ (lane & 15)) << 4);  // ((2h)^s)<<4
    int dsb[4];
    #pragma unroll
    for (int n = 0; n < 4; n++)
        dsb[n] = n * 8192 + l31 * 256 + t16;

    // col pids (tile-invariant)
    int pc[4];
    #pragma unroll
    for (int n = 0; n < 4; n++) pc[n] = pidc[n * 32 + l31];

    float colp4[4] = {0.f, 0.f, 0.f, 0.f};   // accumulates across ALL 8 tiles
    const int  target = (lane & 3) + 4 * ((lane >> 3) & 3);  // reg holding diag
    const bool ownl   = (h == ((lane >> 2) & 1));            // h matches row bit2

    #pragma unroll
    for (int i = 0; i < 8; i++) {
        const int band  = band0 + i;
        const int rbase = band * 128 + wid * 32;

        // prefetch NEXT tile's A (issued before MFMAs -> latency hidden)
        intx8 afn[4];
        if (i < 7) {
            const unsigned char* ga =
                za_f8 + (size_t)(rbase + 128 + l31) * DDIM + h * 32;
            #pragma unroll
            for (int ks = 0; ks < 4; ks++)
                afn[ks] = *(const intx8*)(ga + ks * 64);
        }

        // row pids for this tile (used only in epilogue -> load covered by MFMAs)
        int prw[16];
        #pragma unroll
        for (int reg = 0; reg < 16; reg++)
            prw[reg] = pid[rbase + (reg & 3) + 8 * (reg >> 2) + 4 * h];

        // ---- GEMM: 32 ds_read_b128 + 16 mfma_scale
        floatx16 acc[4];
        #pragma unroll
        for (int n = 0; n < 4; n++) acc[n] = (floatx16)0.0f;

        #pragma unroll
        for (int ks = 0; ks < 4; ks++) {
            #pragma unroll
            for (int n = 0; n < 4; n++) {
                intx4 lo = *(const intx4*)(Bs + (dsb[n] ^ ((ks * 4 + 0) << 4)));
                intx4 hi = *(const intx4*)(Bs + (dsb[n] ^ ((ks * 4 + 1) << 4)));
                intx8 b;
                b[0] = lo[0]; b[1] = lo[1]; b[2] = lo[2]; b[3] = lo[3];
                b[4] = hi[0]; b[5] = hi[1]; b[6] = hi[2]; b[7] = hi[3];
                acc[n] = __builtin_amdgcn_mfma_scale_f32_32x32x64_f8f6f4(
                    afc[ks], b, acc[n], 0, 0, 0, 0x7F7F7F7F, 0, 0x7F7F7F7F);
            }
        }

        // ---- epilogue (wave-local, no syncs)
        float rowp[16];
        #pragma unroll
        for (int r = 0; r < 16; r++) rowp[r] = 0.f;

        #pragma unroll
        for (int n = 0; n < 4; n++) {
            const int pcn = pc[n];
            #pragma unroll
            for (int reg = 0; reg < 16; reg++) {
                float e = __builtin_amdgcn_exp2f(fmaf(acc[n][reg], SC_L2E, -C2));
                e = (prw[reg] != pcn) ? e : 0.f;
                colp4[n] += e;
                rowp[reg] += e;
            }
            if (band == cbb && n == wid) {   // diagonal fixup (wave-uniform)
                float vd = 0.f;
                #pragma unroll
                for (int reg = 0; reg < 16; reg++)
                    vd = (reg == target) ? acc[n][reg] : vd;   // cndmask chain
                float ed = __builtin_amdgcn_exp2f(fmaf(vd, SC_L2E, -C2));
                ed = ownl ? ed : 0.f;
                colp4[n] += ed;
                #pragma unroll
                for (int reg = 0; reg < 16; reg++)
                    rowp[reg] += (reg == target) ? ed : 0.f;   // ed=0 if !ownl
                if (ownl) posv[band * 128 + wid * 32 + l31] = vd * SCALE;
            }
        }

        // row sums: split-tree reduce of rowp[16] over the 32-lane half
#define RED(bit, c)                                                        \
        _Pragma("unroll")                                                  \
        for (int _i = 0; _i < (c); _i++) {                                 \
            float _s = (lane & (bit)) ? rowp[_i] : rowp[_i + (c)];         \
            float _o = __shfl_xor(_s, (bit), 64);                          \
            rowp[_i] = ((lane & (bit)) ? rowp[_i + (c)] : rowp[_i]) + _o;  \
        }
        RED(1, 8) RED(2, 4) RED(4, 2) RED(8, 1)
#undef RED
        rowp[0] += __shfl_xor(rowp[0], 16, 64);
        if ((lane & 16) == 0) {
            const int reg = ((lane & 1) << 3) | ((lane & 2) << 1)
                          | ((lane & 4) >> 1) | ((lane & 8) >> 3);
            const int rl  = (reg & 3) + 8 * (reg >> 2) + 4 * h;
            atomicAdd(&s_row[rbase + rl], rowp[0]);
        }

        // rotate pipelined A
        if (i < 7) {
            #pragma unroll
            for (int ks = 0; ks < 4; ks++) afc[ks] = afn[ks];
        }
    }

    // ---- col flush (once per block, after all 8 tiles)
    #pragma unroll
    for (int n = 0; n < 4; n++)
        colp4[n] += __shfl_xor(colp4[n], 32, 64);
    if (lane < 32) {
        #pragma unroll
        for (int n = 0; n < 4; n++)
            atomicAdd(&colsum[n * 32 + lane], colp4[n]);
    }
    __syncthreads();
    if (tid < 128) atomicAdd(&s_col[col0g + tid], colsum[tid]);
}

// ---------------------------------------------------------------- finalize (+ scalar write)
__global__ __launch_bounds__(256) void finalize_rows(
    const int* __restrict__ pid,
    const float* __restrict__ s_row, const float* __restrict__ s_col,
    const float* __restrict__ posv,
    float* __restrict__ total, int* __restrict__ flag, int* __restrict__ cnt,
    float* __restrict__ out)
{
    const int i = blockIdx.x * 256 + threadIdx.x;
    const float p = posv[i];
    const float c = (logf(s_row[i]) + C_OFF - p)
                  + (logf(s_col[i]) + C_OFF - p);

    float v = c;
    #pragma unroll
    for (int off = 32; off > 0; off >>= 1) v += __shfl_down(v, off, 64);
    if ((threadIdx.x & 63) == 0) atomicAdd(total, v);

    const unsigned long long m = __ballot(pid[i] != pid[0]);
    if (m != 0ull && (threadIdx.x & 63) == 0) atomicOr(flag, 1);

    __syncthreads();
    __threadfence();
    if (threadIdx.x == 0) {
        const int done = atomicAdd(cnt, 1);
        if (done == (int)gridDim.x - 1) {
            const float t = atomicAdd(total, 0.0f);
            const int   f = atomicOr(flag, 0);
            out[0] = f ? t / (2.0f * (float)BSZ) : 0.0f;
        }
    }
}

// ---------------------------------------------------------------- launcher
extern "C" void kernel_launch(void* const* d_in, const int* in_sizes, int n_in,
                              void* d_out, int out_size, void* d_ws, size_t ws_size,
                              hipStream_t stream)
{
    const float* za  = (const float*)d_in[0];
    const float* zt  = (const float*)d_in[1];
    const int*   pid = (const int*)d_in[2];
    float* out = (float*)d_out;

    // ws: za_f8 2MB | zt_perm 2MB | s_row[8192] s_col[8192] total flag cnt posv[8192]
    unsigned char* za_f8   = (unsigned char*)d_ws;
    unsigned char* zt_perm = za_f8 + (size_t)BSZ * DDIM;
    float*  s_row   = (float*)(zt_perm + (size_t)BSZ * DDIM);
    float*  s_col   = s_row + BSZ;
    float*  total   = s_col + BSZ;
    int*    flag    = (int*)(total + 1);
    int*    cnt     = flag + 1;
    float*  posv    = (float*)(cnt + 1);

    prep_kernel<<<dim3(2048), 256, 0, stream>>>(za, zt, za_f8, zt_perm, s_row);

    sim_fused<<<dim3(512), 256, 0, stream>>>(za_f8, zt_perm, pid,
                                             s_row, s_col, posv);

    finalize_rows<<<dim3(BSZ / 256), 256, 0, stream>>>(
        pid, s_row, s_col, posv, total, flag, cnt, out);
}